// Round 17
// baseline (2097.708 us; speedup 1.0000x reference)
//
#include <hip/hip_runtime.h>
#include <hip/hip_bf16.h>

#define B_ 128
#define T_ 200
#define H_ 512
#define G_ 2048   // 4*H
#define E_ 300

typedef unsigned short u16;
typedef unsigned int u32;

using f32x4 = __attribute__((ext_vector_type(4))) float;
using s16x8 = __attribute__((ext_vector_type(8))) short;

__device__ __forceinline__ u16 f2bf(float f) {
  u32 u = __builtin_bit_cast(u32, f);
  u32 r = (u + 0x7fffu + ((u >> 16) & 1u)) >> 16;   // RNE
  return (u16)r;
}
__device__ __forceinline__ float bf2f(u16 s) {
  return __builtin_bit_cast(float, (u32)s << 16);
}

// ---- device-coherent (L1/L2-bypass) memory ops: sc0 sc1 (PROVEN r3-r16) ---
__device__ __forceinline__ s16x8 ld_h16_sc(const void* p) {
  s16x8 r;
  asm volatile("global_load_dwordx4 %0, %1, off sc0 sc1" : "=v"(r) : "v"(p));
  return r;
}
__device__ __forceinline__ void st_h_sc(void* p, u32 v) {   // low 16 bits
  asm volatile("global_store_short %0, %1, off sc0 sc1" :: "v"(p), "v"(v));
}
__device__ __forceinline__ u32 ld_flag_sc(const void* p) {
  u32 r;
  asm volatile("global_load_dword %0, %1, off sc0 sc1\n\ts_waitcnt vmcnt(0)"
               : "=v"(r) : "v"(p) : "memory");
  return r;
}
__device__ __forceinline__ void st_flag_sc(void* p, u32 v) {
  asm volatile("global_store_dword %0, %1, off sc0 sc1" :: "v"(p), "v"(v) : "memory");
}

// ---------------------------------------------------------------------------
// mask bits: mb[t*4 + w] = bit i <- (tok[(w*32+i)*T + t] != 0)
// ---------------------------------------------------------------------------
__global__ __launch_bounds__(64) void mask_k(
    const int* __restrict__ tok, u32* __restrict__ mb)
{
  const int idx = blockIdx.x * 64 + threadIdx.x;
  if (idx >= T_ * 4) return;
  const int t = idx >> 2, w = idx & 3;
  u32 bits = 0;
  for (int i = 0; i < 32; ++i)
    bits |= (tok[(w * 32 + i) * T_ + t] != 0 ? 1u : 0u) << i;
  mb[idx] = bits;
}

// ---------------------------------------------------------------------------
// Persistent LSTM, v17 = r16 fused design, de-redundified:
//  - waves 1-2 stage the 16x320 emb tile ONCE per step (float4 loads, cvt,
//    swizzled LDS araw) pre-barrier-A (hidden under wave0's poll)
//  - waves 4-7 produce xg(t+1) from araw via ds_read_b128 + 10 MFMA in the
//    B->C window (hidden under wave0's epilogue), into the xr parity ring
// araw single-buffer safety: write(pre-A(t)) < read(B(t)..C(t)) < next
// write(pre-A(t+1)) - each ordered by the intervening barriers.
// xr slot s=(t+1)&1: written B(t)..C(t); previously read B(t-1)..C(t-1);
// ordered by C(t-1). h/flag protocol byte-identical to r10.
// ---------------------------------------------------------------------------
template<int TRACK_C>
__global__ __launch_bounds__(512, 2) void lstm_rec(
    const int* __restrict__ tok, const float* __restrict__ emb,
    const float* __restrict__ Wih, const float* __restrict__ bih,
    const float* __restrict__ bhh, const float* __restrict__ Whh,
    u16* __restrict__ hbuf, const float* __restrict__ c0in,
    float* __restrict__ cOut, float* __restrict__ mhOut,
    u32* __restrict__ flags, const u32* __restrict__ maskb)
{
  __shared__ f32x4 red[8][4][64];   // 32 KB: [kslice][q][lane]
  __shared__ f32x4 xr[2][4][64];    // 8 KB: xg ring [slot][q][lane]
  __shared__ u16 araw[16 * 320];    // 10 KB: staged emb tile (swizzled rows)
  const int tid = threadIdx.x;
  const int wv = tid >> 6, ln = tid & 63, lr = ln & 15, lq = ln >> 4;
  const int grp = (int)blockIdx.x >> 5, jt = (int)blockIdx.x & 31;
  const int j0 = jt * 16, bg0 = grp * 16;
  u32* gflags = flags + grp * 512;          // 32 flags x 16 u32 pad

  // Whh B frags (all waves): Bf[q][ks] = Whh[q*512+j0+lr][wv*64+ks*32+lq*8..]
  s16x8 Bf[4][2];
#pragma unroll
  for (int q = 0; q < 4; ++q) {
    const float* wr = Whh + (size_t)(q * H_ + j0 + lr) * H_ + wv * 64 + lq * 8;
#pragma unroll
    for (int ks = 0; ks < 2; ++ks) {
      const float* wp = wr + ks * 32;
      s16x8 f;
#pragma unroll
      for (int i = 0; i < 8; ++i) f[i] = (short)f2bf(wp[i]);
      Bf[q][ks] = f;
    }
  }

  // waves 4..7: Wih frags for quadrant q: Wf[ks] = Wih[q*512+j0+lr][ks*32+lq*8..]
  const int qq = wv - 4;
  s16x8 Wf[10];
  if (wv >= 4) {
    const float* wr = Wih + (size_t)(qq * H_ + j0 + lr) * E_;
#pragma unroll
    for (int ks = 0; ks < 10; ++ks) {
      s16x8 f;
#pragma unroll
      for (int i = 0; i < 8; ++i) {
        const int k = ks * 32 + lq * 8 + i;
        f[i] = (short)((k < E_) ? f2bf(wr[k]) : (u16)0);
      }
      Wf[ks] = f;
    }
  }

  // wave0: cell state + bias[q]
  float c[4], mb[4], bias[4];
#pragma unroll
  for (int r = 0; r < 4; ++r) {
    const int b = bg0 + lq * 4 + r;
    float cv = 0.f;
    if (!TRACK_C && wv == 0) cv = c0in[b * H_ + j0 + lr];
    c[r] = cv;
    mb[r] = TRACK_C ? cv : 0.f;
  }
  if (wv == 0) {
#pragma unroll
    for (int q = 0; q < 4; ++q) {
      const int g = q * H_ + j0 + lr;
      bias[q] = bih[g] + bhh[g];
    }
  }

  // staging role constants (waves 1-2): 128 lanes cover 16 rows x 8 parts
  const int sidx = (wv - 1) * 64 + ln;       // 0..127 for wv in {1,2}
  const int srow = sidx & 15, spart = sidx >> 4;
  char* sdst = (char*)araw + srow * 640;
  const int sswz = (srow & 7) << 4;

  // ---- prime: stage raw(0), produce xr[0] ----
  if (wv == 1 || wv == 2) {
    const float* er = emb + (size_t)tok[(bg0 + srow) * T_ + 0] * E_;
#pragma unroll
    for (int ch = 0; ch < 10; ++ch) {
      const int k = spart * 40 + ch * 4;
      f32x4 v = (k + 4 <= E_) ? *(const f32x4*)(er + k) : (f32x4){0.f,0.f,0.f,0.f};
      *(u32*)(sdst + ((k * 2) ^ sswz))     = (u32)f2bf(v[0]) | ((u32)f2bf(v[1]) << 16);
      *(u32*)(sdst + ((k * 2 + 4) ^ sswz)) = (u32)f2bf(v[2]) | ((u32)f2bf(v[3]) << 16);
    }
  }
  __syncthreads();
  if (wv >= 4) {
    const char* abase = (const char*)araw + lr * 640;
    const int aswz = (lr & 7) << 4;
    f32x4 xacc = {0.f, 0.f, 0.f, 0.f};
#pragma unroll
    for (int ks = 0; ks < 10; ++ks) {
      s16x8 af = *(const s16x8*)(abase + ((ks * 64 + lq * 16) ^ aswz));
      xacc = __builtin_amdgcn_mfma_f32_16x16x32_bf16(af, Wf[ks], xacc, 0, 0, 0);
    }
    xr[0][qq][ln] = xacc;
  }
  __syncthreads();

  const u32* pp = gflags + (ln & 31) * 16;   // 32 flags, x2 lane duplication
  const int mword = grp >> 1, mshift = (grp & 1) * 16;

  for (int t = 0; t < T_; ++t) {
    const u16* hrd = hbuf + (t & 1) * (B_ * H_);
    u16* hwr = hbuf + ((t + 1) & 1) * (B_ * H_);

    u32 mku = 0;
    if (wv == 0) {
      mku = maskb[t * 4 + mword] >> mshift;
      // poll the group's 32 producer flags (tight loop) - r10 verbatim
      if (t > 0) {
        int guard = 0;
        for (;;) {
          u32 v = ld_flag_sc(pp);
          if (__all((int)(v >= (u32)t))) break;
          if (++guard > (1 << 22)) break;   // bail out instead of hanging
          __builtin_amdgcn_s_sleep(1);
        }
      }
    } else if ((wv == 1 || wv == 2) && t + 1 < T_) {
      // stage raw emb tile for t+1 (hidden under wave0's poll)
      const float* er = emb + (size_t)tok[(bg0 + srow) * T_ + (t + 1)] * E_;
#pragma unroll
      for (int ch = 0; ch < 10; ++ch) {
        const int k = spart * 40 + ch * 4;
        f32x4 v = (k + 4 <= E_) ? *(const f32x4*)(er + k) : (f32x4){0.f,0.f,0.f,0.f};
        *(u32*)(sdst + ((k * 2) ^ sswz))     = (u32)f2bf(v[0]) | ((u32)f2bf(v[1]) << 16);
        *(u32*)(sdst + ((k * 2 + 4) ^ sswz)) = (u32)f2bf(v[2]) | ((u32)f2bf(v[3]) << 16);
      }
    }
    __syncthreads();                         // barrier A: h_t ready (+ araw staged)
    __builtin_amdgcn_sched_barrier(0);

    // h_t loads (coherent): rows = bg0+lr, k = wv*64 + ks*32 + lq*8
    s16x8 ha0, ha1;
    const u16* hb = hrd + (size_t)(bg0 + lr) * H_ + wv * 64 + lq * 8;
    ha0 = ld_h16_sc(hb);
    ha1 = ld_h16_sc(hb + 32);
    asm volatile("s_waitcnt vmcnt(0)" ::: "memory");
    __builtin_amdgcn_sched_barrier(0);

    f32x4 acc[4];
#pragma unroll
    for (int q = 0; q < 4; ++q) {
      acc[q] = __builtin_amdgcn_mfma_f32_16x16x32_bf16(ha0, Bf[q][0],
                   (f32x4){0.f, 0.f, 0.f, 0.f}, 0, 0, 0);
      acc[q] = __builtin_amdgcn_mfma_f32_16x16x32_bf16(ha1, Bf[q][1], acc[q], 0, 0, 0);
    }

    if (wv > 0) {
#pragma unroll
      for (int q = 0; q < 4; ++q) red[wv][q][ln] = acc[q];
    }
    __syncthreads();                         // barrier B: red ready
    if (wv == 0) {
#pragma unroll
      for (int kv = 1; kv < 8; ++kv)
#pragma unroll
        for (int q = 0; q < 4; ++q) acc[q] += red[kv][q][ln];
      // xg term from the LDS ring (slot t&1)
      f32x4 xv[4];
#pragma unroll
      for (int q = 0; q < 4; ++q) xv[q] = xr[t & 1][q][ln];
      const bool last = (t == T_ - 1);
#pragma unroll
      for (int r = 0; r < 4; ++r) {
        const int b = bg0 + lq * 4 + r;
        const float gi = acc[0][r] + xv[0][r] + bias[0];
        const float gf = acc[1][r] + xv[1][r] + bias[1];
        const float gG = acc[2][r] + xv[2][r] + bias[2];
        const float go = acc[3][r] + xv[3][r] + bias[3];
        const float si = 1.f / (1.f + __expf(-gi));
        const float sf = 1.f / (1.f + __expf(-gf));
        const float so = 1.f / (1.f + __expf(-go));
        const float tg = 2.f / (1.f + __expf(-2.f * gG)) - 1.f;
        const float cn = sf * c[r] + si * tg;
        const float tc = 2.f / (1.f + __expf(-2.f * cn)) - 1.f;
        const float hn = so * tc;
        c[r] = cn;
        if ((mku >> (lq * 4 + r)) & 1u) mb[r] = TRACK_C ? cn : hn;
        if (!last) st_h_sc(hwr + (size_t)b * H_ + j0 + lr, (u32)f2bf(hn));
      }
      if (t + 1 < T_) {
        asm volatile("s_waitcnt vmcnt(0)" ::: "memory");   // drain h stores
        if (ln == 0) st_flag_sc(gflags + jt * 16, (u32)(t + 1));
      }
    } else if (wv >= 4 && t + 1 < T_) {
      // produce xg(t+1) from araw (hidden under wave0's epilogue)
      const char* abase = (const char*)araw + lr * 640;
      const int aswz = (lr & 7) << 4;
      f32x4 xacc = {0.f, 0.f, 0.f, 0.f};
#pragma unroll
      for (int ks = 0; ks < 10; ++ks) {
        s16x8 af = *(const s16x8*)(abase + ((ks * 64 + lq * 16) ^ aswz));
        xacc = __builtin_amdgcn_mfma_f32_16x16x32_bf16(af, Wf[ks], xacc, 0, 0, 0);
      }
      xr[(t + 1) & 1][qq][ln] = xacc;
    }
    __syncthreads();                         // barrier C (orders araw/xr reuse)
  }

  if (wv == 0) {
#pragma unroll
    for (int r = 0; r < 4; ++r) {
      const int b = bg0 + lq * 4 + r;
      if (TRACK_C) cOut[b * H_ + j0 + lr] = mb[r];
      else         mhOut[b * H_ + j0 + lr] = mb[r];
    }
  }
}

// ---------------------------------------------------------------------------
// head: logits = [mh, sim] @ fcW^T + fcb ; log_softmax
// ---------------------------------------------------------------------------
__global__ __launch_bounds__(128) void final_k(
    const float* __restrict__ mh, const float* __restrict__ sim,
    const float* __restrict__ fcW, const float* __restrict__ fcb,
    float* __restrict__ out)
{
  const int b = threadIdx.x;
  float l[3];
#pragma unroll
  for (int cc = 0; cc < 3; ++cc) {
    const float* wr = fcW + cc * (H_ + 1);
    float s = fcb[cc] + sim[b] * wr[H_];
    for (int j = 0; j < H_; ++j) s += mh[b * H_ + j] * wr[j];
    l[cc] = s;
  }
  const float m = fmaxf(l[0], fmaxf(l[1], l[2]));
  const float lse = m + logf(__expf(l[0] - m) + __expf(l[1] - m) + __expf(l[2] - m));
  out[b * 3 + 0] = l[0] - lse;
  out[b * 3 + 1] = l[1] - lse;
  out[b * 3 + 2] = l[2] - lse;
}

extern "C" void kernel_launch(void* const* d_in, const int* in_sizes, int n_in,
                              void* d_out, int out_size, void* d_ws, size_t ws_size,
                              hipStream_t stream) {
  const int*   prem = (const int*)d_in[0];
  const int*   hypo = (const int*)d_in[1];
  const float* sim  = (const float*)d_in[2];
  const float* emb  = (const float*)d_in[3];
  const float* WihP = (const float*)d_in[4];
  const float* WhhP = (const float*)d_in[5];
  const float* bihP = (const float*)d_in[6];
  const float* bhhP = (const float*)d_in[7];
  const float* WihH = (const float*)d_in[8];
  const float* WhhH = (const float*)d_in[9];
  const float* bihH = (const float*)d_in[10];
  const float* bhhH = (const float*)d_in[11];
  const float* fcW  = (const float*)d_in[12];
  const float* fcb  = (const float*)d_in[13];
  float* out = (float*)d_out;

  char* ws = (char*)d_ws;
  const size_t HB_OFF = 0;                                // 2 x 128 x 512 bf16
  const size_t CL_OFF = HB_OFF + (size_t)2 * B_ * H_ * 2;
  const size_t MH_OFF = CL_OFF + (size_t)B_ * H_ * 4;
  const size_t FL_OFF = MH_OFF + (size_t)B_ * H_ * 4;     // 2 x 16 KB flags
  const size_t MK_OFF = FL_OFF + 32768;                   // 2 x 4 KB maskbits
  const size_t NEED   = MK_OFF + 8192;                    // ~1.1 MB
  if (ws_size < NEED) return;  // visible failure instead of OOB corruption

  u16*   hbuf  = (u16*)(ws + HB_OFF);
  float* cLast = (float*)(ws + CL_OFF);
  float* mh    = (float*)(ws + MH_OFF);
  u32*   flagsP = (u32*)(ws + FL_OFF);        // 8 grp x 32 x 64B
  u32*   flagsH = flagsP + 4096;
  u32*   maskbP = (u32*)(ws + MK_OFF);        // 200 x 4 u32
  u32*   maskbH = maskbP + 1024;

  hipMemsetAsync(ws + FL_OFF, 0, 32768, stream);          // both flag regions

  mask_k<<<13, 64, 0, stream>>>(prem, maskbP);
  mask_k<<<13, 64, 0, stream>>>(hypo, maskbH);
  hipMemsetAsync(hbuf, 0, (size_t)B_ * H_ * 2, stream);   // h0 = 0 (buffer 0)
  lstm_rec<1><<<256, 512, 0, stream>>>(prem, emb, WihP, bihP, bhhP, WhhP,
                                       hbuf, nullptr, cLast, nullptr,
                                       flagsP, maskbP);
  hipMemsetAsync(hbuf, 0, (size_t)B_ * H_ * 2, stream);   // h0 = 0 (buffer 0)
  lstm_rec<0><<<256, 512, 0, stream>>>(hypo, emb, WihH, bihH, bhhH, WhhH,
                                       hbuf, cLast, nullptr, mh,
                                       flagsH, maskbH);
  final_k<<<1, 128, 0, stream>>>(mh, sim, fcW, fcb, out);
}

// Round 18
// 2020.212 us; speedup vs baseline: 1.0384x; 1.0384x over previous
//
#include <hip/hip_runtime.h>
#include <hip/hip_bf16.h>

#define B_ 128
#define T_ 200
#define H_ 512
#define G_ 2048   // 4*H
#define E_ 300

typedef unsigned short u16;
typedef unsigned int u32;

using f32x4 = __attribute__((ext_vector_type(4))) float;
using s16x8 = __attribute__((ext_vector_type(8))) short;
using u32x2 = __attribute__((ext_vector_type(2))) u32;

__device__ __forceinline__ u16 f2bf(float f) {
  u32 u = __builtin_bit_cast(u32, f);
  u32 r = (u + 0x7fffu + ((u >> 16) & 1u)) >> 16;   // RNE
  return (u16)r;
}
__device__ __forceinline__ float bf2f(u16 s) {
  return __builtin_bit_cast(float, (u32)s << 16);
}

// ---- device-coherent (L1/L2-bypass) memory ops: sc0 sc1 (PROVEN r3-r17) ---
__device__ __forceinline__ s16x8 ld_h16_sc(const void* p) {
  s16x8 r;
  asm volatile("global_load_dwordx4 %0, %1, off sc0 sc1" : "=v"(r) : "v"(p));
  return r;
}
__device__ __forceinline__ void st_h_sc(void* p, u32 v) {   // low 16 bits
  asm volatile("global_store_short %0, %1, off sc0 sc1" :: "v"(p), "v"(v));
}
__device__ __forceinline__ u32 ld_flag_sc(const void* p) {
  u32 r;
  asm volatile("global_load_dword %0, %1, off sc0 sc1\n\ts_waitcnt vmcnt(0)"
               : "=v"(r) : "v"(p) : "memory");
  return r;
}
__device__ __forceinline__ void st_flag_sc(void* p, u32 v) {
  asm volatile("global_store_dword %0, %1, off sc0 sc1" :: "v"(p), "v"(v) : "memory");
}

// ---------------------------------------------------------------------------
// prep_k: one launch replacing 2x wih_cvt + 2x mask_k + flags memset +
// hbuf(buffer0) memset. Block ranges partition disjoint outputs:
//   [0,2560)      WihP -> WbP (bf16, K padded 300->320)
//   [2560,5120)   WihH -> WbH
//   [5120,5127)   mask bits for prem (800) then hypo (800)
//   [5127,5159)   zero both flag regions (8192 u32)
//   [5159,5287)   zero hbuf buffer 0   (32768 u32)
// ---------------------------------------------------------------------------
__global__ __launch_bounds__(256) void prep_k(
    const float* __restrict__ WihP, const float* __restrict__ WihH,
    u16* __restrict__ WbP, u16* __restrict__ WbH,
    const int* __restrict__ prem, const int* __restrict__ hypo,
    u32* __restrict__ maskbP, u32* __restrict__ maskbH,
    u32* __restrict__ flags32, u32* __restrict__ hbuf32)
{
  const int bid = blockIdx.x, tid = threadIdx.x;
  if (bid < 5120) {
    const int half = bid >= 2560;
    const int idx = (bid - half * 2560) * 256 + tid;   // < 655360
    const int row = idx / 320, k = idx - row * 320;
    const float* W = half ? WihH : WihP;
    u16* Wb = half ? WbH : WbP;
    const float v = (k < E_) ? W[row * E_ + k] : 0.f;
    Wb[idx] = f2bf(v);
  } else if (bid < 5127) {
    const int g = (bid - 5120) * 256 + tid;            // < 1792, need 1600
    if (g >= 1600) return;
    const int half = g >= 800;
    const int idx = g - half * 800;
    const int t = idx >> 2, w = idx & 3;
    const int* tok = half ? hypo : prem;
    u32 bits = 0;
    for (int i = 0; i < 32; ++i)
      bits |= (tok[(w * 32 + i) * T_ + t] != 0 ? 1u : 0u) << i;
    (half ? maskbH : maskbP)[idx] = bits;
  } else if (bid < 5159) {
    const int i = (bid - 5127) * 256 + tid;            // < 8192
    flags32[i] = 0;
  } else {
    const int i = (bid - 5159) * 256 + tid;            // < 32768
    hbuf32[i] = 0;
  }
}

// ---------------------------------------------------------------------------
// xg GEMM, output layout xg[m][j 512][q 4] bf16 with m = t*128 + b.
// (verified end-to-end in rounds 6/7/10/14)
// ---------------------------------------------------------------------------
__global__ __launch_bounds__(256) void xg_gemm(
    const int* __restrict__ tok, const float* __restrict__ emb,
    const u16* __restrict__ Wb, const float* __restrict__ bih,
    const float* __restrict__ bhh, u16* __restrict__ xg)
{
  __shared__ u16 Al[64 * 320];
  __shared__ u16 Bl[32 * 320];
  __shared__ int tks[64];
  const int tid = threadIdx.x;
  const int bx = blockIdx.x;
  const int m0 = bx * 64;            // m = t*128 + b ; block: t = bx>>1, b0 = (bx&1)*64
  if (tid < 64) tks[tid] = tok[((bx & 1) * 64 + tid) * T_ + (bx >> 1)];
  __syncthreads();
  {
    const int row = tid >> 2, part = tid & 3;
    const float* erow = emb + (size_t)tks[row] * E_;
    char* base = (char*)Al + row * 640;
    const int swz = (row & 7) << 4;
#pragma unroll
    for (int i = 0; i < 40; ++i) {
      const int kw = part * 40 + i;
      const int k = kw * 2;
      const float v0 = (k < E_) ? erow[k] : 0.f;
      const float v1 = (k + 1 < E_) ? erow[k + 1] : 0.f;
      *(u32*)(base + ((kw * 4) ^ swz)) = (u32)f2bf(v0) | ((u32)f2bf(v1) << 16);
    }
  }
  __syncthreads();
  const int wv = tid >> 6, ln = tid & 63, lr = ln & 15, lq = ln >> 4;
  const int arow = wv * 16 + lr;
  const char* abase = (const char*)Al + arow * 640;
  const int aswz = (arow & 7) << 4;
  const int brow = tid >> 3, bpart = tid & 7;
  char* bdst = (char*)Bl + brow * 640;
  const int bswz = (brow & 7) << 4;
  const char* b0base = (const char*)Bl + lr * 640;
  const char* b1base = (const char*)Bl + (16 + lr) * 640;
  const int bswz2 = (lr & 7) << 4;

  for (int ni = 0; ni < 8; ++ni) {
    const int n0 = blockIdx.y * 256 + ni * 32;
    {
      const u16* src = Wb + (size_t)(n0 + brow) * 320 + bpart * 40;
#pragma unroll
      for (int i = 0; i < 5; ++i) {
        s16x8 v = *(const s16x8*)(src + i * 8);
        *(s16x8*)(bdst + (((bpart * 5 + i) * 16) ^ bswz)) = v;
      }
    }
    __syncthreads();
    f32x4 acc0 = {0.f, 0.f, 0.f, 0.f}, acc1 = {0.f, 0.f, 0.f, 0.f};
#pragma unroll
    for (int ks = 0; ks < 10; ++ks) {
      const int kb = ks * 64 + lq * 16;
      s16x8 af  = *(const s16x8*)(abase  + (kb ^ aswz));
      s16x8 bf0 = *(const s16x8*)(b0base + (kb ^ bswz2));
      s16x8 bf1 = *(const s16x8*)(b1base + (kb ^ bswz2));
      acc0 = __builtin_amdgcn_mfma_f32_16x16x32_bf16(af, bf0, acc0, 0, 0, 0);
      acc1 = __builtin_amdgcn_mfma_f32_16x16x32_bf16(af, bf1, acc1, 0, 0, 0);
    }
    const int qc = n0 >> 9;            // gate quadrant (uniform per 32-tile)
    const int jA = (n0 & 511) + lr;    // j within quadrant
#pragma unroll
    for (int r = 0; r < 4; ++r) {
      const int m = m0 + wv * 16 + lq * 4 + r;
      const int gA = n0 + lr, gB = n0 + 16 + lr;
      xg[(size_t)m * 2048 + (size_t)jA * 4 + qc]        = f2bf(acc0[r] + bih[gA] + bhh[gA]);
      xg[(size_t)m * 2048 + (size_t)(jA + 16) * 4 + qc] = f2bf(acc1[r] + bih[gB] + bhh[gB]);
    }
    __syncthreads();
  }
}

// ---------------------------------------------------------------------------
// Persistent LSTM recurrence = round-10 structure VERBATIM (best measured:
// 808 us). 8 batch-groups of 16 x 32 j-slice WGs = 256 WGs x 512 thr.
// Wave wv = K-slice [wv*64,+64): 2 UC h-loads + 8 MFMA per step. Wave 0 =
// epilogue wave: 8-way LDS red gather, 4 cells/lane, h stores, drain, flag.
// Poll: wave 0, tight loop, own group's 32 flags. 3 barriers/step (A,B,C —
// r14 proved removing C hurts).
// ---------------------------------------------------------------------------
template<int TRACK_C>
__global__ __launch_bounds__(512, 2) void lstm_rec(
    const u16* __restrict__ xg, const float* __restrict__ Whh,
    u16* __restrict__ hbuf, const float* __restrict__ c0in,
    float* __restrict__ cOut, float* __restrict__ mhOut,
    u32* __restrict__ flags, const u32* __restrict__ maskb)
{
  __shared__ f32x4 red[8][4][64];   // 32 KB: [kslice][q][lane]
  const int tid = threadIdx.x;
  const int wv = tid >> 6, ln = tid & 63, lr = ln & 15, lq = ln >> 4;
  const int grp = (int)blockIdx.x >> 5, jt = (int)blockIdx.x & 31;
  const int j0 = jt * 16, bg0 = grp * 16;
  u32* gflags = flags + grp * 512;          // 32 flags x 16 u32 pad

  // persistent B frags: Bf[q][ks] = Whh[q*512+j0+lr][wv*64+ks*32+lq*8 ..+8]
  s16x8 Bf[4][2];
#pragma unroll
  for (int q = 0; q < 4; ++q) {
    const float* wr = Whh + (size_t)(q * H_ + j0 + lr) * H_ + wv * 64 + lq * 8;
#pragma unroll
    for (int ks = 0; ks < 2; ++ks) {
      const float* wp = wr + ks * 32;
      s16x8 f;
#pragma unroll
      for (int i = 0; i < 8; ++i) f[i] = (short)f2bf(wp[i]);
      Bf[q][ks] = f;
    }
  }

  // epilogue state (wave 0): 4 cells/lane: b = bg0 + lq*4 + r, j = j0 + lr
  float c[4], mb[4];
#pragma unroll
  for (int r = 0; r < 4; ++r) {
    const int b = bg0 + lq * 4 + r;
    float cv = 0.f;
    if (!TRACK_C && wv == 0) cv = c0in[b * H_ + j0 + lr];
    c[r] = cv;
    mb[r] = TRACK_C ? cv : 0.f;
  }

  const u32* pp = gflags + (ln & 31) * 16;   // 32 flags, x2 lane duplication
  const int mword = grp >> 1, mshift = (grp & 1) * 16;

  for (int t = 0; t < T_; ++t) {
    const u16* hrd = hbuf + (t & 1) * (B_ * H_);
    u16* hwr = hbuf + ((t + 1) & 1) * (B_ * H_);

    // wave 0: prefetch xg (u32x2 = 4 gates/cell) + mask word (cached loads)
    u32x2 gxp[4];
    u32 mku = 0;
    if (wv == 0) {
      mku = maskb[t * 4 + mword] >> mshift;
#pragma unroll
      for (int r = 0; r < 4; ++r) {
        const int b = bg0 + lq * 4 + r;
        gxp[r] = *(const u32x2*)(xg + (size_t)(t * 128 + b) * 2048
                                    + (size_t)(j0 + lr) * 4);
      }
      // poll the group's 32 producer flags (tight loop)
      if (t > 0) {
        int guard = 0;
        for (;;) {
          u32 v = ld_flag_sc(pp);
          if (__all((int)(v >= (u32)t))) break;
          if (++guard > (1 << 22)) break;   // bail out instead of hanging
          __builtin_amdgcn_s_sleep(1);
        }
      }
    }
    __syncthreads();                         // barrier A: h_t ready
    __builtin_amdgcn_sched_barrier(0);

    // h_t loads (coherent): rows = bg0+lr, k = wv*64 + ks*32 + lq*8
    s16x8 ha0, ha1;
    const u16* hb = hrd + (size_t)(bg0 + lr) * H_ + wv * 64 + lq * 8;
    ha0 = ld_h16_sc(hb);
    ha1 = ld_h16_sc(hb + 32);
    asm volatile("s_waitcnt vmcnt(0)" ::: "memory");
    __builtin_amdgcn_sched_barrier(0);

    f32x4 acc[4];
#pragma unroll
    for (int q = 0; q < 4; ++q) {
      acc[q] = __builtin_amdgcn_mfma_f32_16x16x32_bf16(ha0, Bf[q][0],
                   (f32x4){0.f, 0.f, 0.f, 0.f}, 0, 0, 0);
      acc[q] = __builtin_amdgcn_mfma_f32_16x16x32_bf16(ha1, Bf[q][1], acc[q], 0, 0, 0);
    }

    if (wv > 0) {
#pragma unroll
      for (int q = 0; q < 4; ++q) red[wv][q][ln] = acc[q];
    }
    __syncthreads();                         // barrier B: red ready
    if (wv == 0) {
#pragma unroll
      for (int kv = 1; kv < 8; ++kv)
#pragma unroll
        for (int q = 0; q < 4; ++q) acc[q] += red[kv][q][ln];
      const bool last = (t == T_ - 1);
#pragma unroll
      for (int r = 0; r < 4; ++r) {
        const int b = bg0 + lq * 4 + r;
        const u32 lo = gxp[r][0], hi = gxp[r][1];
        const float gi = acc[0][r] + bf2f((u16)lo);
        const float gf = acc[1][r] + bf2f((u16)(lo >> 16));
        const float gG = acc[2][r] + bf2f((u16)hi);
        const float go = acc[3][r] + bf2f((u16)(hi >> 16));
        const float si = 1.f / (1.f + __expf(-gi));
        const float sf = 1.f / (1.f + __expf(-gf));
        const float so = 1.f / (1.f + __expf(-go));
        const float tg = 2.f / (1.f + __expf(-2.f * gG)) - 1.f;
        const float cn = sf * c[r] + si * tg;
        const float tc = 2.f / (1.f + __expf(-2.f * cn)) - 1.f;
        const float hn = so * tc;
        c[r] = cn;
        if ((mku >> (lq * 4 + r)) & 1u) mb[r] = TRACK_C ? cn : hn;
        if (!last) st_h_sc(hwr + (size_t)b * H_ + j0 + lr, (u32)f2bf(hn));
      }
      if (t + 1 < T_) {
        asm volatile("s_waitcnt vmcnt(0)" ::: "memory");   // drain h stores
        if (ln == 0) st_flag_sc(gflags + jt * 16, (u32)(t + 1));
      }
    }
    __syncthreads();                         // barrier C
  }

  if (wv == 0) {
#pragma unroll
    for (int r = 0; r < 4; ++r) {
      const int b = bg0 + lq * 4 + r;
      if (TRACK_C) cOut[b * H_ + j0 + lr] = mb[r];
      else         mhOut[b * H_ + j0 + lr] = mb[r];
    }
  }
}

// ---------------------------------------------------------------------------
// head: logits = [mh, sim] @ fcW^T + fcb ; log_softmax
// ---------------------------------------------------------------------------
__global__ __launch_bounds__(128) void final_k(
    const float* __restrict__ mh, const float* __restrict__ sim,
    const float* __restrict__ fcW, const float* __restrict__ fcb,
    float* __restrict__ out)
{
  const int b = threadIdx.x;
  float l[3];
#pragma unroll
  for (int cc = 0; cc < 3; ++cc) {
    const float* wr = fcW + cc * (H_ + 1);
    float s = fcb[cc] + sim[b] * wr[H_];
    for (int j = 0; j < H_; ++j) s += mh[b * H_ + j] * wr[j];
    l[cc] = s;
  }
  const float m = fmaxf(l[0], fmaxf(l[1], l[2]));
  const float lse = m + logf(__expf(l[0] - m) + __expf(l[1] - m) + __expf(l[2] - m));
  out[b * 3 + 0] = l[0] - lse;
  out[b * 3 + 1] = l[1] - lse;
  out[b * 3 + 2] = l[2] - lse;
}

extern "C" void kernel_launch(void* const* d_in, const int* in_sizes, int n_in,
                              void* d_out, int out_size, void* d_ws, size_t ws_size,
                              hipStream_t stream) {
  const int*   prem = (const int*)d_in[0];
  const int*   hypo = (const int*)d_in[1];
  const float* sim  = (const float*)d_in[2];
  const float* emb  = (const float*)d_in[3];
  const float* WihP = (const float*)d_in[4];
  const float* WhhP = (const float*)d_in[5];
  const float* bihP = (const float*)d_in[6];
  const float* bhhP = (const float*)d_in[7];
  const float* WihH = (const float*)d_in[8];
  const float* WhhH = (const float*)d_in[9];
  const float* bihH = (const float*)d_in[10];
  const float* bhhH = (const float*)d_in[11];
  const float* fcW  = (const float*)d_in[12];
  const float* fcb  = (const float*)d_in[13];
  float* out = (float*)d_out;

  char* ws = (char*)d_ws;
  const size_t XG_BYTES = (size_t)B_ * T_ * G_ * 2;        // 104,857,600
  const size_t HB_OFF  = XG_BYTES;                         // 2 x 128 x 512 bf16
  const size_t CL_OFF  = HB_OFF + (size_t)2 * B_ * H_ * 2;
  const size_t MH_OFF  = CL_OFF + (size_t)B_ * H_ * 4;
  const size_t FL_OFF  = MH_OFF + (size_t)B_ * H_ * 4;     // 2 x 16 KB flags
  const size_t MK_OFF  = FL_OFF + 32768;                   // 2 x 4 KB maskbits
  const size_t WBP_OFF = MK_OFF + 8192;
  const size_t WBH_OFF = WBP_OFF + (size_t)G_ * 320 * 2;
  const size_t NEED    = WBH_OFF + (size_t)G_ * 320 * 2;   // ~108.3 MB
  if (ws_size < NEED) return;  // visible failure instead of OOB corruption

  u16*   xg    = (u16*)ws;
  u16*   hbuf  = (u16*)(ws + HB_OFF);
  float* cLast = (float*)(ws + CL_OFF);
  float* mh    = (float*)(ws + MH_OFF);
  u32*   flagsP = (u32*)(ws + FL_OFF);        // 8 grp x 32 x 64B
  u32*   flagsH = flagsP + 4096;
  u32*   maskbP = (u32*)(ws + MK_OFF);        // 200 x 4 u32
  u32*   maskbH = maskbP + 1024;
  u16*   WbP   = (u16*)(ws + WBP_OFF);
  u16*   WbH   = (u16*)(ws + WBH_OFF);

  // single prep launch: both Wih cvts, both masks, zero flags + hbuf buf0
  prep_k<<<5287, 256, 0, stream>>>(WihP, WihH, WbP, WbH, prem, hypo,
                                   maskbP, maskbH, (u32*)(ws + FL_OFF),
                                   (u32*)hbuf);

  dim3 gG(400, 8);
  xg_gemm<<<gG, 256, 0, stream>>>(prem, emb, WbP, bihP, bhhP, xg);
  lstm_rec<1><<<256, 512, 0, stream>>>(xg, WhhP, hbuf, nullptr, cLast, nullptr, flagsP, maskbP);
  xg_gemm<<<gG, 256, 0, stream>>>(hypo, emb, WbH, bihH, bhhH, xg);
  hipMemsetAsync(hbuf, 0, (size_t)B_ * H_ * 2, stream);   // h0 = 0 (buffer 0)
  lstm_rec<0><<<256, 512, 0, stream>>>(xg, WhhH, hbuf, cLast, nullptr, mh, flagsH, maskbH);
  final_k<<<1, 128, 0, stream>>>(mh, sim, fcW, fcb, out);
}